// Round 3
// baseline (430.537 us; speedup 1.0000x reference)
//
#include <hip/hip_runtime.h>

typedef unsigned short u16;
typedef __attribute__((ext_vector_type(8))) short bf16x8;
typedef __attribute__((ext_vector_type(4))) float f32x4;

#define MFMA16(a, b, c) __builtin_amdgcn_mfma_f32_16x16x32_bf16(a, b, c, 0, 0, 0)

__device__ __forceinline__ u16 f2bf(float f) {
  union { float f; unsigned u; } v; v.f = f;
  unsigned r = v.u + 0x7fffu + ((v.u >> 16) & 1u);
  return (u16)(r >> 16);
}

__device__ __forceinline__ unsigned pkbf(float lo, float hi) {
  unsigned r;
  asm("v_cvt_pk_bf16_f32 %0, %1, %2" : "=v"(r) : "v"(lo), "v"(hi));
  return r;
}

// In-register transpose (verified r2): input a[t][r] = M[t*16 + g*4 + r][li] (f32),
// output: lane holds bf16 M[g*8+j][li], j=0..7 — the MFMA A/B-operand fragment layout.
__device__ __forceinline__ bf16x8 xform(const float* a0, const float* a1, int srcA, bool hi) {
  unsigned p0 = pkbf(a0[0], a0[1]), p1 = pkbf(a0[2], a0[3]);
  unsigned p2 = pkbf(a1[0], a1[1]), p3 = pkbf(a1[2], a1[3]);
  int srcB = srcA + 16;
  unsigned u0 = __shfl((int)p0, srcA), u1 = __shfl((int)p1, srcA);
  unsigned u2 = __shfl((int)p2, srcA), u3 = __shfl((int)p3, srcA);
  unsigned v0 = __shfl((int)p0, srcB), v1 = __shfl((int)p1, srcB);
  unsigned v2 = __shfl((int)p2, srcB), v3 = __shfl((int)p3, srcB);
  union { bf16x8 v; unsigned w[4]; } o;
  o.w[0] = hi ? u2 : u0; o.w[1] = hi ? u3 : u1;
  o.w[2] = hi ? v2 : v0; o.w[3] = hi ? v3 : v1;
  return o.v;
}

// ---------------- pack: weights -> bf16 fragment layout, bias -> per-lane frag order ----
// wpack  [36 nt][6 ks][64 lane][8]   from wqkv_w[192][576]
// wppack [12 nt][6 ks][64 lane][8]   from wp_w[192][192]
// biasf  [6 h][4 nt][4 mt][64 lane][4]  bias[q=nt*16+(lane&15)][k=mt*16+(lane>>4)*4+r]
__global__ void pack_kernel(const float* __restrict__ wqkv_w,
                            const float* __restrict__ wp_w,
                            const float* __restrict__ bias_table,
                            u16* __restrict__ wpack, u16* __restrict__ wppack,
                            float* __restrict__ biasf) {
  int i = blockIdx.x * 256 + threadIdx.x;
  if (i < 110592) {
    int j = i & 7, l = (i >> 3) & 63;
    int rest = i >> 9;
    int ks = rest % 6, nt = rest / 6;
    int k = ks * 32 + (l >> 4) * 8 + j;
    int n = nt * 16 + (l & 15);
    wpack[i] = f2bf(wqkv_w[k * 576 + n]);
  } else if (i < 147456) {
    int i2 = i - 110592;
    int j = i2 & 7, l = (i2 >> 3) & 63;
    int rest = i2 >> 9;
    int ks = rest % 6, nt = rest / 6;
    int k = ks * 32 + (l >> 4) * 8 + j;
    int n = nt * 16 + (l & 15);
    wppack[i2] = f2bf(wp_w[k * 192 + n]);
  } else if (i < 172032) {
    int i2 = i - 147456;            // 0..24575
    int r = i2 & 3, lane = (i2 >> 2) & 63, mt = (i2 >> 8) & 3, nt = (i2 >> 10) & 3, h = i2 >> 12;
    int q = nt * 16 + (lane & 15);
    int kk = mt * 16 + (lane >> 4) * 4 + r;
    int idx = ((q >> 3) - (kk >> 3) + 7) * 15 + ((q & 7) - (kk & 7) + 7);
    biasf[i2] = bias_table[idx * 6 + h];
  }
}

// ---------------- fully fused: x -> qkv -> attention -> projection -> out ----------------
// 1 block = 1 window (64 tokens); 6 waves = 6 heads. LDS 25.6 KB (xs aliased with ysh).
__global__ __launch_bounds__(384, 4) void win_attn(
    const float* __restrict__ x, const u16* __restrict__ wpack,
    const float* __restrict__ wqkv_b, const float* __restrict__ biasf,
    const u16* __restrict__ wppack, const float* __restrict__ wp_b,
    float* __restrict__ out) {
  __shared__ u16 lds[12800];         // phase1: xs frags [4mt][6ks][64][8]; later: ysh [64][200]
  const int tid = threadIdx.x;
  const int lane = tid & 63;
  const int wv = tid >> 6;           // head
  const int g = lane >> 4, li = lane & 15;
  const int blk = blockIdx.x;
  const int bb = blk / 576, rem = blk % 576, wy = rem / 24, wx = rem % 24;
  const size_t xbase = (size_t)bb * 36864;

  // ---- stage x window into LDS as bf16 A-fragments (lane-linear stores, 0 conflicts) ----
  {
    const int part = tid >> 6, li0 = tid & 15;   // (tid>>4)&3 = g2 implicit in chunk math
    const int rr = li0 >> 3, cc = li0 & 7;
    const float* gp = x + (xbase + (wy * 8 + rr) * 192 + wx * 8 + cc) * 192
                      + part * 32 + ((tid >> 4) & 3) * 8;
    u16* dst = lds + tid * 8;
#pragma unroll
    for (int m = 0; m < 4; ++m) {
      float4 f0 = *(const float4*)gp;
      float4 f1 = *(const float4*)(gp + 4);
      union { bf16x8 v; unsigned w[4]; } o;
      o.w[0] = pkbf(f0.x, f0.y); o.w[1] = pkbf(f0.z, f0.w);
      o.w[2] = pkbf(f1.x, f1.y); o.w[3] = pkbf(f1.z, f1.w);
      *(bf16x8*)dst = o.v;
      gp += 73728;                   // +16 tokens = +2 pixel rows
      dst += 3072;                   // +384 chunks * 8 u16
    }
  }
  __syncthreads();

  const float scale = 0.17677669529663687f;   // 1/sqrt(32)
  const f32x4 zero4 = {0.f, 0.f, 0.f, 0.f};
  const int srcA = (lane & 16) * 2 + li;
  const bool hi = lane >= 32;
  const u16* wbase = wpack + lane * 8;

  // ---- Q^T, K^T = mfma(W_frag, x_frag) ----
  f32x4 qt[2][4], kt[2][4];
#pragma unroll
  for (int i = 0; i < 2; ++i)
#pragma unroll
    for (int mt = 0; mt < 4; ++mt) { qt[i][mt] = zero4; kt[i][mt] = zero4; }
#pragma unroll
  for (int ks = 0; ks < 6; ++ks) {
    bf16x8 af[4];
#pragma unroll
    for (int mt = 0; mt < 4; ++mt)
      af[mt] = *(const bf16x8*)(lds + ((mt * 6 + ks) * 64 + lane) * 8);
#pragma unroll
    for (int i = 0; i < 2; ++i) {
      bf16x8 wq = *(const bf16x8*)(wbase + ((2 * wv + i) * 6 + ks) * 512);
      bf16x8 wk = *(const bf16x8*)(wbase + ((12 + 2 * wv + i) * 6 + ks) * 512);
#pragma unroll
      for (int mt = 0; mt < 4; ++mt) {
        qt[i][mt] = MFMA16(wq, af[mt], qt[i][mt]);
        kt[i][mt] = MFMA16(wk, af[mt], kt[i][mt]);
      }
    }
  }

  float bqa[2][4], bka[2][4];
#pragma unroll
  for (int i = 0; i < 2; ++i) {
    float4 t1 = *(const float4*)(wqkv_b + wv * 32 + i * 16 + g * 4);
    bqa[i][0] = t1.x; bqa[i][1] = t1.y; bqa[i][2] = t1.z; bqa[i][3] = t1.w;
    float4 t2 = *(const float4*)(wqkv_b + 192 + wv * 32 + i * 16 + g * 4);
    bka[i][0] = t2.x; bka[i][1] = t2.y; bka[i][2] = t2.z; bka[i][3] = t2.w;
  }
  bf16x8 qf[4], kf[4];
#pragma unroll
  for (int mt = 0; mt < 4; ++mt) {
    float a0[4], a1[4];
#pragma unroll
    for (int r = 0; r < 4; ++r) {
      a0[r] = (qt[0][mt][r] + bqa[0][r]) * scale;
      a1[r] = (qt[1][mt][r] + bqa[1][r]) * scale;
    }
    qf[mt] = xform(a0, a1, srcA, hi);
#pragma unroll
    for (int r = 0; r < 4; ++r) {
      a0[r] = kt[0][mt][r] + bka[0][r];
      a1[r] = kt[1][mt][r] + bka[1][r];
    }
    kf[mt] = xform(a0, a1, srcA, hi);
  }

  // ---- V = mfma(x_frag, Wv_frag) ----
  f32x4 va[4][2];
#pragma unroll
  for (int mt = 0; mt < 4; ++mt) { va[mt][0] = zero4; va[mt][1] = zero4; }
#pragma unroll
  for (int ks = 0; ks < 6; ++ks) {
    bf16x8 af[4];
#pragma unroll
    for (int mt = 0; mt < 4; ++mt)
      af[mt] = *(const bf16x8*)(lds + ((mt * 6 + ks) * 64 + lane) * 8);
    bf16x8 wv0 = *(const bf16x8*)(wbase + ((24 + 2 * wv) * 6 + ks) * 512);
    bf16x8 wv1 = *(const bf16x8*)(wbase + ((25 + 2 * wv) * 6 + ks) * 512);
#pragma unroll
    for (int mt = 0; mt < 4; ++mt) {
      va[mt][0] = MFMA16(af[mt], wv0, va[mt][0]);
      va[mt][1] = MFMA16(af[mt], wv1, va[mt][1]);
    }
  }
  float bva[2] = { wqkv_b[384 + wv * 32 + li], wqkv_b[384 + wv * 32 + 16 + li] };
  bf16x8 vf[2][2];    // [d-tile i][key-chunk ks2]
#pragma unroll
  for (int i = 0; i < 2; ++i)
#pragma unroll
    for (int ks2 = 0; ks2 < 2; ++ks2) {
      float a0[4], a1[4];
#pragma unroll
      for (int r = 0; r < 4; ++r) {
        a0[r] = va[ks2 * 2][i][r] + bva[i];
        a1[r] = va[ks2 * 2 + 1][i][r] + bva[i];
      }
      vf[i][ks2] = xform(a0, a1, srcA, hi);
    }

  __syncthreads();   // last xs reads done; lds may be reused as ysh below

  // ---- per-q-tile: S^T = mfma(K,Q), softmax, P-frag, Y += P V ----
  const float* bfh = biasf + (wv * 16) * 256 + lane * 4;
  f32x4 yacc[4][2];
#pragma unroll
  for (int nt = 0; nt < 4; ++nt) { yacc[nt][0] = zero4; yacc[nt][1] = zero4; }
#pragma unroll
  for (int nt = 0; nt < 4; ++nt) {
    f32x4 stn[4];
#pragma unroll
    for (int mt = 0; mt < 4; ++mt) stn[mt] = MFMA16(kf[mt], qf[nt], zero4);
    float e[4][4];
    float mx = -1e30f;
#pragma unroll
    for (int mt = 0; mt < 4; ++mt) {
      float4 b4 = *(const float4*)(bfh + (nt * 4 + mt) * 256);
      e[mt][0] = stn[mt][0] + b4.x;
      e[mt][1] = stn[mt][1] + b4.y;
      e[mt][2] = stn[mt][2] + b4.z;
      e[mt][3] = stn[mt][3] + b4.w;
      mx = fmaxf(mx, fmaxf(fmaxf(e[mt][0], e[mt][1]), fmaxf(e[mt][2], e[mt][3])));
    }
    mx = fmaxf(mx, __shfl_xor(mx, 16));
    mx = fmaxf(mx, __shfl_xor(mx, 32));
    float s = 0.f;
#pragma unroll
    for (int mt = 0; mt < 4; ++mt)
#pragma unroll
      for (int r = 0; r < 4; ++r) { e[mt][r] = __expf(e[mt][r] - mx); s += e[mt][r]; }
    s += __shfl_xor(s, 16);
    s += __shfl_xor(s, 32);
    float inv = 1.0f / s;
#pragma unroll
    for (int ks2 = 0; ks2 < 2; ++ks2) {
      float a0[4], a1[4];
#pragma unroll
      for (int r = 0; r < 4; ++r) {
        a0[r] = e[ks2 * 2][r] * inv;
        a1[r] = e[ks2 * 2 + 1][r] * inv;
      }
      bf16x8 pf = xform(a0, a1, srcA, hi);
      yacc[nt][0] = MFMA16(pf, vf[0][ks2], yacc[nt][0]);
      yacc[nt][1] = MFMA16(pf, vf[1][ks2], yacc[nt][1]);
    }
  }

  // ---- stage Y to LDS (ysh[64][200], paired u32 stores) ----
  {
    const int odd = li & 1;
    const int chb = wv * 32 + (odd ? 16 : 0) + (li & ~1);
#pragma unroll
    for (int nt = 0; nt < 4; ++nt)
#pragma unroll
      for (int r = 0; r < 4; ++r) {
        int tok = nt * 16 + g * 4 + r;
        float v0 = yacc[nt][0][r], v1 = yacc[nt][1][r];
        float p0 = __shfl_xor(v0, 1), p1 = __shfl_xor(v1, 1);
        unsigned w0 = odd ? pkbf(p0, v0) : pkbf(v0, p0);
        unsigned w1 = odd ? pkbf(p1, v1) : pkbf(v1, p1);
        *(unsigned*)(lds + tok * 200 + chb) = odd ? w1 : w0;
      }
  }
  __syncthreads();

  // ---- projection: out = Y @ wp + b  (per wave: all 64 rows x its 32 out-cols) ----
  f32x4 acc[4][2];
#pragma unroll
  for (int mt = 0; mt < 4; ++mt) { acc[mt][0] = zero4; acc[mt][1] = zero4; }
#pragma unroll
  for (int ks = 0; ks < 6; ++ks) {
    bf16x8 af2[4];
#pragma unroll
    for (int mt = 0; mt < 4; ++mt)
      af2[mt] = *(const bf16x8*)(lds + (mt * 16 + li) * 200 + ks * 32 + g * 8);
    bf16x8 bw0 = *(const bf16x8*)(wppack + ((wv * 2) * 6 + ks) * 512 + lane * 8);
    bf16x8 bw1 = *(const bf16x8*)(wppack + ((wv * 2 + 1) * 6 + ks) * 512 + lane * 8);
#pragma unroll
    for (int mt = 0; mt < 4; ++mt) {
      acc[mt][0] = MFMA16(af2[mt], bw0, acc[mt][0]);
      acc[mt][1] = MFMA16(af2[mt], bw1, acc[mt][1]);
    }
  }
  const float bb0 = wp_b[wv * 32 + li], bb1 = wp_b[wv * 32 + 16 + li];
#pragma unroll
  for (int mt = 0; mt < 4; ++mt)
#pragma unroll
    for (int r = 0; r < 4; ++r) {
      int tok = mt * 16 + g * 4 + r;
      size_t base = (xbase + (wy * 8 + (tok >> 3)) * 192 + wx * 8 + (tok & 7)) * 192 + wv * 32 + li;
      out[base] = acc[mt][0][r] + bb0;
      out[base + 16] = acc[mt][1][r] + bb1;
    }
}

extern "C" void kernel_launch(void* const* d_in, const int* in_sizes, int n_in,
                              void* d_out, int out_size, void* d_ws, size_t ws_size,
                              hipStream_t stream) {
  (void)in_sizes; (void)n_in; (void)out_size; (void)ws_size;
  const float* x          = (const float*)d_in[0];
  const float* wqkv_w     = (const float*)d_in[1];
  const float* wqkv_b     = (const float*)d_in[2];
  const float* wp_w       = (const float*)d_in[3];
  const float* wp_b       = (const float*)d_in[4];
  const float* bias_table = (const float*)d_in[5];
  float* out = (float*)d_out;
  char* ws = (char*)d_ws;
  u16* wpack   = (u16*)(ws);              // 221184 B
  u16* wppack  = (u16*)(ws + 221184);     //  73728 B
  float* biasf = (float*)(ws + 294912);   //  98304 B

  pack_kernel<<<672, 256, 0, stream>>>(wqkv_w, wp_w, bias_table, wpack, wppack, biasf);
  win_attn<<<4608, 384, 0, stream>>>(x, wpack, wqkv_b, biasf, wppack, wp_b, out);
}